// Round 1
// baseline (308.417 us; speedup 1.0000x reference)
//
#include <hip/hip_runtime.h>
#include <math.h>

#define N_MEM   50000
#define P_TOT   4096
#define DDIM    256
#define HDIM    480
#define WDIM    640
#define CHUNKS  64
#define CHUNK_SZ 782          // ceil(50000/64)
#define THR2    0.01f
#define EPSF    1e-8f

// ---------------- K1: pix2world ----------------
__global__ void k_world(const float* __restrict__ points,
                        const float* __restrict__ depth,
                        const float* __restrict__ pose,
                        const float* __restrict__ Kmat,
                        float4* __restrict__ pts_out,
                        int* __restrict__ valid_out,
                        float* __restrict__ accum)
{
    int p = blockIdx.x * 256 + threadIdx.x;
    if (p == 0) { accum[0] = 0.f; accum[1] = 0.f; }
    if (p >= P_TOT) return;
    int b = p >> 9;
    const float* K = Kmat + b * 9;
    float a00=K[0],a01=K[1],a02=K[2],a10=K[3],a11=K[4],a12=K[5],a20=K[6],a21=K[7],a22=K[8];
    float det = a00*(a11*a22-a12*a21) - a01*(a10*a22-a12*a20) + a02*(a10*a21-a11*a20);
    float id = 1.0f/det;
    float i00=(a11*a22-a12*a21)*id, i01=(a02*a21-a01*a22)*id, i02=(a01*a12-a02*a11)*id;
    float i10=(a12*a20-a10*a22)*id, i11=(a00*a22-a02*a20)*id, i12=(a02*a10-a00*a12)*id;
    float i20=(a10*a21-a11*a20)*id, i21=(a01*a20-a00*a21)*id, i22=(a00*a11-a01*a10)*id;

    float u = points[p*2+0], v = points[p*2+1];
    float uc = fminf(fmaxf(u, 0.f), (float)WDIM - 1.001f);
    float vc = fminf(fmaxf(v, 0.f), (float)HDIM - 1.001f);
    float u0 = floorf(uc), v0 = floorf(vc);
    float du = uc - u0, dv = vc - v0;
    int u0i = (int)u0, v0i = (int)v0;
    const float* dm = depth + (size_t)b * HDIM * WDIM;
    float d00 = dm[v0i*WDIM + u0i];
    float d01 = dm[v0i*WDIM + u0i + 1];
    float d10 = dm[(v0i+1)*WDIM + u0i];
    float d11 = dm[(v0i+1)*WDIM + u0i + 1];
    float d = d00*(1.f-du)*(1.f-dv) + d01*du*(1.f-dv) + d10*(1.f-du)*dv + d11*du*dv;

    float cx = (i00*u + i01*v + i02) * d;
    float cy = (i10*u + i11*v + i12) * d;
    float cz = (i20*u + i21*v + i22) * d;
    const float* T = pose + b * 12;
    float wx = T[0]*cx + T[1]*cy + T[2]*cz  + T[3];
    float wy = T[4]*cx + T[5]*cy + T[6]*cz  + T[7];
    float wz = T[8]*cx + T[9]*cy + T[10]*cz + T[11];
    int val = (d > 0.f) && isfinite(wx) && isfinite(wy) && isfinite(wz);
    float4 o = val ? make_float4(wx, wy, wz, 0.f) : make_float4(1e6f, 1e6f, 1e6f, 0.f);
    pts_out[p] = o;
    valid_out[p] = val;
}

// ---------------- K2: partial argmin over mem_pts chunks ----------------
// grid (8, 64): x = point-block (512 pts), y = chunk. 2 points/thread.
__global__ __launch_bounds__(256) void k_dist(const float4* __restrict__ pts,
                                              const float* __restrict__ mem_pts,
                                              float* __restrict__ part_d,
                                              int* __restrict__ part_i)
{
    __shared__ float smx[CHUNK_SZ], smy[CHUNK_SZ], smz[CHUNK_SZ], smm[CHUNK_SZ];
    int pb = blockIdx.x;
    int ch = blockIdx.y;
    int t = threadIdx.x;
    int j0 = ch * CHUNK_SZ;
    int cnt = min(CHUNK_SZ, N_MEM - j0);
    for (int j = t; j < cnt; j += 256) {
        float mx = mem_pts[(j0 + j) * 3 + 0];
        float my = mem_pts[(j0 + j) * 3 + 1];
        float mz = mem_pts[(j0 + j) * 3 + 2];
        smx[j] = mx; smy[j] = my; smz[j] = mz;
        smm[j] = mx*mx + my*my + mz*mz;
    }
    __syncthreads();
    int p0 = pb * 512 + t;
    int p1 = p0 + 256;
    float4 P0 = pts[p0], P1 = pts[p1];
    float pp0 = P0.x*P0.x + P0.y*P0.y + P0.z*P0.z;
    float pp1 = P1.x*P1.x + P1.y*P1.y + P1.z*P1.z;
    float bd0 = 3.4e38f, bd1 = 3.4e38f;
    int bi0 = 0, bi1 = 0;
    for (int j = 0; j < cnt; ++j) {
        float mx = smx[j], my = smy[j], mz = smz[j], mm = smm[j];
        float dot0 = P0.x*mx + P0.y*my + P0.z*mz;
        float dot1 = P1.x*mx + P1.y*my + P1.z*mz;
        float d0 = pp0 - 2.f*dot0 + mm;
        float d1 = pp1 - 2.f*dot1 + mm;
        if (d0 < bd0) { bd0 = d0; bi0 = j0 + j; }   // strict <: first occurrence
        if (d1 < bd1) { bd1 = d1; bi1 = j0 + j; }
    }
    part_d[p0 * CHUNKS + ch] = bd0;
    part_i[p0 * CHUNKS + ch] = bi0;
    part_d[p1 * CHUNKS + ch] = bd1;
    part_i[p1 * CHUNKS + ch] = bi1;
}

// ---------------- K3: reduce 64 chunk-partials per point (1 wave/point) ----------------
__global__ __launch_bounds__(256) void k_reduce(const float* __restrict__ part_d,
                                                const int* __restrict__ part_i,
                                                const int* __restrict__ valid,
                                                int* __restrict__ idx_out,
                                                int* __restrict__ match_out)
{
    int t = threadIdx.x;
    int w = t >> 6;
    int lane = t & 63;
    int p = blockIdx.x * 4 + w;
    float d = part_d[p * CHUNKS + lane];
    int i = part_i[p * CHUNKS + lane];
    for (int off = 32; off; off >>= 1) {
        float od = __shfl_down(d, off);
        int   oi = __shfl_down(i, off);
        if (od < d || (od == d && oi < i)) { d = od; i = oi; }  // ties -> lowest idx (np argmin)
    }
    if (lane == 0) {
        idx_out[p] = i;
        match_out[p] = (d < THR2) && valid[p];
    }
}

// ---------------- K4: scan unmatched -> write slots (widx), n_match ----------------
__global__ __launch_bounds__(256) void k_scan(const int* __restrict__ match,
                                              const int* __restrict__ valid,
                                              const int* __restrict__ idx,
                                              const int* __restrict__ next_ptr,
                                              int* __restrict__ widx,
                                              int* __restrict__ unm_out,
                                              float* __restrict__ dout)
{
    __shared__ int su[256];
    __shared__ int sm[256];
    int t = threadIdx.x;
    int base = t * 16;
    int um[16]; int usum = 0, msum = 0;
    for (int k = 0; k < 16; k++) {
        int m = match[base + k];
        int v = valid[base + k];
        int u = (!m) && v;
        um[k] = u; usum += u; msum += m;
    }
    su[t] = usum; sm[t] = msum;
    __syncthreads();
    for (int off = 1; off < 256; off <<= 1) {
        int a = su[t], b = (t >= off) ? su[t - off] : 0;
        int c = sm[t], d = (t >= off) ? sm[t - off] : 0;
        __syncthreads();
        su[t] = a + b; sm[t] = c + d;
        __syncthreads();
    }
    int excl = su[t] - usum;
    int np_ = *next_ptr;
    int run = excl;
    for (int k = 0; k < 16; k++) {
        int wv;
        if (um[k]) { run += 1; wv = (np_ + run - 1) % N_MEM; }
        else       { wv = idx[base + k]; }
        widx[base + k] = wv;
        unm_out[base + k] = um[k];
    }
    if (t == 255) dout[1] = (float)sm[255];   // n_match
}

// ---------------- K5: copy mem state to outputs ----------------
__global__ void k_copy(const float* __restrict__ mem_pts,
                       const float* __restrict__ mem_desc,
                       float* __restrict__ out_pts,
                       float* __restrict__ out_desc)
{
    long i = (long)blockIdx.x * 256 + threadIdx.x;
    long stride = (long)gridDim.x * 256;
    const float2* ds = (const float2*)mem_desc;
    float2* dd = (float2*)out_desc;                 // 8B-aligned (offset 600008 B)
    for (long k = i; k < (long)N_MEM * DDIM / 2; k += stride) dd[k] = ds[k];
    const float2* ps = (const float2*)mem_pts;
    float2* pd = (float2*)out_pts;
    for (long k = i; k < (long)N_MEM * 3 / 2; k += stride) pd[k] = ps[k];
}

// ---------------- K6: last-write-wins winner resolution ----------------
__global__ void k_winner(const int* __restrict__ widx, int* __restrict__ winner)
{
    int p = blockIdx.x * 256 + threadIdx.x;
    if (p < P_TOT) atomicMax(&winner[widx[p]], p);
}

// ---------------- K7: scatter updates (block per point; only winner writes) ----------------
__global__ __launch_bounds__(256) void k_scatter(const int* __restrict__ widx,
                                                 const int* __restrict__ match,
                                                 const int* __restrict__ unm,
                                                 const int* __restrict__ winner,
                                                 const float* __restrict__ desc,
                                                 const float4* __restrict__ pts,
                                                 const float* __restrict__ mem_pts,
                                                 const float* __restrict__ mem_desc,
                                                 float* __restrict__ out_pts,
                                                 float* __restrict__ out_desc)
{
    __shared__ float sw[4];
    int p = blockIdx.x;
    int wi = widx[p];
    if (winner[wi] != p) return;          // uniform across block
    int t = threadIdx.x;
    int m = match[p], u = unm[p];
    float dsg = desc[p * DDIM + t];
    float old = mem_desc[wi * DDIM + t];
    float val;
    if (m) {
        float up = old * 0.5f + dsg * 0.5f;
        float s = up * up;
        for (int off = 32; off; off >>= 1) s += __shfl_down(s, off);
        if ((t & 63) == 0) sw[t >> 6] = s;
        __syncthreads();
        float tot = sw[0] + sw[1] + sw[2] + sw[3];
        val = up / (sqrtf(tot) + EPSF);
    } else if (u) {
        val = dsg;
    } else {
        val = old;                        // invalid point: rewrite old value (np semantics)
    }
    out_desc[wi * DDIM + t] = val;
    if (t == 0) {
        float px, py, pz;
        if (u) { float4 P = pts[p]; px = P.x; py = P.y; pz = P.z; }
        else   { px = mem_pts[wi*3]; py = mem_pts[wi*3+1]; pz = mem_pts[wi*3+2]; }
        out_pts[wi*3+0] = px; out_pts[wi*3+1] = py; out_pts[wi*3+2] = pz;
    }
}

// ---------------- K8: cosine loss accumulation ----------------
__global__ __launch_bounds__(256) void k_loss(const int* __restrict__ match,
                                              const int* __restrict__ valid,
                                              const int* __restrict__ idx,
                                              const float* __restrict__ desc,
                                              const float* __restrict__ mem_desc,
                                              float* __restrict__ accum)
{
    __shared__ float sw[12];
    int p = blockIdx.x;
    int t = threadIdx.x;
    float dv = desc[p * DDIM + t];
    int m = match[p];
    float mv = m ? mem_desc[idx[p] * DDIM + t] : dv;
    float sdd = dv * dv, smm = mv * mv, sdm = dv * mv;
    for (int off = 32; off; off >>= 1) {
        sdd += __shfl_down(sdd, off);
        smm += __shfl_down(smm, off);
        sdm += __shfl_down(sdm, off);
    }
    if ((t & 63) == 0) { int w = t >> 6; sw[w] = sdd; sw[4+w] = smm; sw[8+w] = sdm; }
    __syncthreads();
    if (t == 0) {
        float a = sw[0] + sw[1] + sw[2] + sw[3];
        float b = sw[4] + sw[5] + sw[6] + sw[7];
        float c = sw[8] + sw[9] + sw[10] + sw[11];
        float nd = fmaxf(sqrtf(a), EPSF);
        float nm = fmaxf(sqrtf(b), EPSF);
        float cosv = c / (nd * nm);
        if (valid[p]) { atomicAdd(&accum[0], cosv); atomicAdd(&accum[1], 1.f); }
    }
}

__global__ void k_final(const float* __restrict__ accum, float* __restrict__ dout)
{
    float nv = fmaxf(accum[1], 1.f);
    dout[0] = 1.f - accum[0] / nv;
}

extern "C" void kernel_launch(void* const* d_in, const int* in_sizes, int n_in,
                              void* d_out, int out_size, void* d_ws, size_t ws_size,
                              hipStream_t stream)
{
    const float* points   = (const float*)d_in[0];
    const float* depth    = (const float*)d_in[1];
    const float* pose     = (const float*)d_in[2];
    const float* Kmat     = (const float*)d_in[3];
    const float* desc     = (const float*)d_in[4];
    const float* mem_pts  = (const float*)d_in[5];
    const float* mem_desc = (const float*)d_in[6];
    const int*   next_ptr = (const int*)d_in[7];

    float* out      = (float*)d_out;
    float* out_pts  = out + 2;
    float* out_desc = out + 2 + (long)N_MEM * 3;

    char* ws = (char*)d_ws;
    float4* pts_ws  = (float4*)(ws);                 //  65536 B
    int* valid_ws   = (int*)(ws + 65536);            //  16384 B
    int* idx_ws     = (int*)(ws + 81920);            //  16384 B
    int* match_ws   = (int*)(ws + 98304);            //  16384 B
    int* widx_ws    = (int*)(ws + 114688);           //  16384 B
    int* unm_ws     = (int*)(ws + 131072);           //  16384 B
    int* winner_ws  = (int*)(ws + 147456);           // 200000 B
    float* accum    = (float*)(ws + 347456);         //      8 B

    // Big partial-argmin arrays live in the not-yet-written out_desc region;
    // they are fully consumed (k_reduce) before k_copy overwrites the region.
    float* part_d = out_desc;                        // 4096*64 floats = 1 MB
    int*   part_i = (int*)(out_desc + P_TOT * CHUNKS);

    hipMemsetAsync(winner_ws, 0xFF, N_MEM * sizeof(int), stream);   // winner = -1

    k_world  <<<16, 256, 0, stream>>>(points, depth, pose, Kmat, pts_ws, valid_ws, accum);
    k_dist   <<<dim3(8, CHUNKS), 256, 0, stream>>>(pts_ws, mem_pts, part_d, part_i);
    k_reduce <<<P_TOT / 4, 256, 0, stream>>>(part_d, part_i, valid_ws, idx_ws, match_ws);
    k_scan   <<<1, 256, 0, stream>>>(match_ws, valid_ws, idx_ws, next_ptr, widx_ws, unm_ws, out);
    k_copy   <<<4096, 256, 0, stream>>>(mem_pts, mem_desc, out_pts, out_desc);
    k_winner <<<P_TOT / 256, 256, 0, stream>>>(widx_ws, winner_ws);
    k_scatter<<<P_TOT, 256, 0, stream>>>(widx_ws, match_ws, unm_ws, winner_ws,
                                         desc, pts_ws, mem_pts, mem_desc, out_pts, out_desc);
    k_loss   <<<P_TOT, 256, 0, stream>>>(match_ws, valid_ws, idx_ws, desc, mem_desc, accum);
    k_final  <<<1, 1, 0, stream>>>(accum, out);
}

// Round 2
// 214.607 us; speedup vs baseline: 1.4371x; 1.4371x over previous
//
#include <hip/hip_runtime.h>
#include <math.h>

#define N_MEM   50000
#define P_TOT   4096
#define DDIM    256
#define HDIM    480
#define WDIM    640
#define CHUNKS  64
#define CHUNK_SZ 782          // ceil(50000/64)
#define THR2    0.01f
#define EPSF    1e-8f

// ---------------- K1: pix2world ----------------
__global__ void k_world(const float* __restrict__ points,
                        const float* __restrict__ depth,
                        const float* __restrict__ pose,
                        const float* __restrict__ Kmat,
                        float4* __restrict__ pts_out,
                        int* __restrict__ valid_out)
{
    int p = blockIdx.x * 256 + threadIdx.x;
    if (p >= P_TOT) return;
    int b = p >> 9;
    const float* K = Kmat + b * 9;
    float a00=K[0],a01=K[1],a02=K[2],a10=K[3],a11=K[4],a12=K[5],a20=K[6],a21=K[7],a22=K[8];
    float det = a00*(a11*a22-a12*a21) - a01*(a10*a22-a12*a20) + a02*(a10*a21-a11*a20);
    float id = 1.0f/det;
    float i00=(a11*a22-a12*a21)*id, i01=(a02*a21-a01*a22)*id, i02=(a01*a12-a02*a11)*id;
    float i10=(a12*a20-a10*a22)*id, i11=(a00*a22-a02*a20)*id, i12=(a02*a10-a00*a12)*id;
    float i20=(a10*a21-a11*a20)*id, i21=(a01*a20-a00*a21)*id, i22=(a00*a11-a01*a10)*id;

    float u = points[p*2+0], v = points[p*2+1];
    float uc = fminf(fmaxf(u, 0.f), (float)WDIM - 1.001f);
    float vc = fminf(fmaxf(v, 0.f), (float)HDIM - 1.001f);
    float u0 = floorf(uc), v0 = floorf(vc);
    float du = uc - u0, dv = vc - v0;
    int u0i = (int)u0, v0i = (int)v0;
    const float* dm = depth + (size_t)b * HDIM * WDIM;
    float d00 = dm[v0i*WDIM + u0i];
    float d01 = dm[v0i*WDIM + u0i + 1];
    float d10 = dm[(v0i+1)*WDIM + u0i];
    float d11 = dm[(v0i+1)*WDIM + u0i + 1];
    float d = d00*(1.f-du)*(1.f-dv) + d01*du*(1.f-dv) + d10*(1.f-du)*dv + d11*du*dv;

    float cx = (i00*u + i01*v + i02) * d;
    float cy = (i10*u + i11*v + i12) * d;
    float cz = (i20*u + i21*v + i22) * d;
    const float* T = pose + b * 12;
    float wx = T[0]*cx + T[1]*cy + T[2]*cz  + T[3];
    float wy = T[4]*cx + T[5]*cy + T[6]*cz  + T[7];
    float wz = T[8]*cx + T[9]*cy + T[10]*cz + T[11];
    int val = (d > 0.f) && isfinite(wx) && isfinite(wy) && isfinite(wz);
    float4 o = val ? make_float4(wx, wy, wz, 0.f) : make_float4(1e6f, 1e6f, 1e6f, 0.f);
    pts_out[p] = o;
    valid_out[p] = val;
}

// ---------------- K2: partial argmin over mem_pts chunks ----------------
// grid (8, 64): x = point-block (512 pts), y = chunk. 2 points/thread.
__global__ __launch_bounds__(256) void k_dist(const float4* __restrict__ pts,
                                              const float* __restrict__ mem_pts,
                                              float* __restrict__ part_d,
                                              int* __restrict__ part_i)
{
    __shared__ float smx[CHUNK_SZ], smy[CHUNK_SZ], smz[CHUNK_SZ], smm[CHUNK_SZ];
    int pb = blockIdx.x;
    int ch = blockIdx.y;
    int t = threadIdx.x;
    int j0 = ch * CHUNK_SZ;
    int cnt = min(CHUNK_SZ, N_MEM - j0);
    for (int j = t; j < cnt; j += 256) {
        float mx = mem_pts[(j0 + j) * 3 + 0];
        float my = mem_pts[(j0 + j) * 3 + 1];
        float mz = mem_pts[(j0 + j) * 3 + 2];
        smx[j] = mx; smy[j] = my; smz[j] = mz;
        smm[j] = mx*mx + my*my + mz*mz;
    }
    __syncthreads();
    int p0 = pb * 512 + t;
    int p1 = p0 + 256;
    float4 P0 = pts[p0], P1 = pts[p1];
    float pp0 = P0.x*P0.x + P0.y*P0.y + P0.z*P0.z;
    float pp1 = P1.x*P1.x + P1.y*P1.y + P1.z*P1.z;
    float bd0 = 3.4e38f, bd1 = 3.4e38f;
    int bi0 = 0, bi1 = 0;
    for (int j = 0; j < cnt; ++j) {
        float mx = smx[j], my = smy[j], mz = smz[j], mm = smm[j];
        float dot0 = P0.x*mx + P0.y*my + P0.z*mz;
        float dot1 = P1.x*mx + P1.y*my + P1.z*mz;
        float d0 = pp0 - 2.f*dot0 + mm;
        float d1 = pp1 - 2.f*dot1 + mm;
        if (d0 < bd0) { bd0 = d0; bi0 = j0 + j; }   // strict <: first occurrence
        if (d1 < bd1) { bd1 = d1; bi1 = j0 + j; }
    }
    part_d[p0 * CHUNKS + ch] = bd0;
    part_i[p0 * CHUNKS + ch] = bi0;
    part_d[p1 * CHUNKS + ch] = bd1;
    part_i[p1 * CHUNKS + ch] = bi1;
}

// ---------------- K3: reduce 64 chunk-partials per point (1 wave/point) ----------------
__global__ __launch_bounds__(256) void k_reduce(const float* __restrict__ part_d,
                                                const int* __restrict__ part_i,
                                                const int* __restrict__ valid,
                                                int* __restrict__ idx_out,
                                                int* __restrict__ match_out)
{
    int t = threadIdx.x;
    int w = t >> 6;
    int lane = t & 63;
    int p = blockIdx.x * 4 + w;
    float d = part_d[p * CHUNKS + lane];
    int i = part_i[p * CHUNKS + lane];
    for (int off = 32; off; off >>= 1) {
        float od = __shfl_down(d, off);
        int   oi = __shfl_down(i, off);
        if (od < d || (od == d && oi < i)) { d = od; i = oi; }  // ties -> lowest idx (np argmin)
    }
    if (lane == 0) {
        idx_out[p] = i;
        match_out[p] = (d < THR2) && valid[p];
    }
}

// ---------------- K4: scan unmatched -> write slots (widx), n_match ----------------
__global__ __launch_bounds__(256) void k_scan(const int* __restrict__ match,
                                              const int* __restrict__ valid,
                                              const int* __restrict__ idx,
                                              const int* __restrict__ next_ptr,
                                              int* __restrict__ widx,
                                              int* __restrict__ unm_out,
                                              float* __restrict__ dout)
{
    __shared__ int su[256];
    __shared__ int sm[256];
    int t = threadIdx.x;
    int base = t * 16;
    int um[16]; int usum = 0, msum = 0;
    for (int k = 0; k < 16; k++) {
        int m = match[base + k];
        int v = valid[base + k];
        int u = (!m) && v;
        um[k] = u; usum += u; msum += m;
    }
    su[t] = usum; sm[t] = msum;
    __syncthreads();
    for (int off = 1; off < 256; off <<= 1) {
        int a = su[t], b = (t >= off) ? su[t - off] : 0;
        int c = sm[t], d = (t >= off) ? sm[t - off] : 0;
        __syncthreads();
        su[t] = a + b; sm[t] = c + d;
        __syncthreads();
    }
    int excl = su[t] - usum;
    int np_ = *next_ptr;
    int run = excl;
    for (int k = 0; k < 16; k++) {
        int wv;
        if (um[k]) { run += 1; wv = (np_ + run - 1) % N_MEM; }
        else       { wv = idx[base + k]; }
        widx[base + k] = wv;
        unm_out[base + k] = um[k];
    }
    if (t == 255) dout[1] = (float)sm[255];   // n_match
}

// ---------------- K5: copy mem state to outputs ----------------
__global__ void k_copy(const float* __restrict__ mem_pts,
                       const float* __restrict__ mem_desc,
                       float* __restrict__ out_pts,
                       float* __restrict__ out_desc)
{
    long i = (long)blockIdx.x * 256 + threadIdx.x;
    long stride = (long)gridDim.x * 256;
    const float2* ds = (const float2*)mem_desc;
    float2* dd = (float2*)out_desc;                 // 8B-aligned (offset 600008 B)
    for (long k = i; k < (long)N_MEM * DDIM / 2; k += stride) dd[k] = ds[k];
    const float2* ps = (const float2*)mem_pts;
    float2* pd = (float2*)out_pts;
    for (long k = i; k < (long)N_MEM * 3 / 2; k += stride) pd[k] = ps[k];
}

// ---------------- K6: last-write-wins winner resolution ----------------
__global__ void k_winner(const int* __restrict__ widx, int* __restrict__ winner)
{
    int p = blockIdx.x * 256 + threadIdx.x;
    if (p < P_TOT) atomicMax(&winner[widx[p]], p);
}

// ---------------- K7: scatter updates (block per point; only winner writes) ----------------
__global__ __launch_bounds__(256) void k_scatter(const int* __restrict__ widx,
                                                 const int* __restrict__ match,
                                                 const int* __restrict__ unm,
                                                 const int* __restrict__ winner,
                                                 const float* __restrict__ desc,
                                                 const float4* __restrict__ pts,
                                                 const float* __restrict__ mem_pts,
                                                 const float* __restrict__ mem_desc,
                                                 float* __restrict__ out_pts,
                                                 float* __restrict__ out_desc)
{
    __shared__ float sw[4];
    int p = blockIdx.x;
    int wi = widx[p];
    if (winner[wi] != p) return;          // uniform across block
    int t = threadIdx.x;
    int m = match[p], u = unm[p];
    float dsg = desc[p * DDIM + t];
    float old = mem_desc[wi * DDIM + t];
    float val;
    if (m) {
        float up = old * 0.5f + dsg * 0.5f;
        float s = up * up;
        for (int off = 32; off; off >>= 1) s += __shfl_down(s, off);
        if ((t & 63) == 0) sw[t >> 6] = s;
        __syncthreads();
        float tot = sw[0] + sw[1] + sw[2] + sw[3];
        val = up / (sqrtf(tot) + EPSF);
    } else if (u) {
        val = dsg;
    } else {
        val = old;                        // invalid point: rewrite old value (np semantics)
    }
    out_desc[wi * DDIM + t] = val;
    if (t == 0) {
        float px, py, pz;
        if (u) { float4 P = pts[p]; px = P.x; py = P.y; pz = P.z; }
        else   { px = mem_pts[wi*3]; py = mem_pts[wi*3+1]; pz = mem_pts[wi*3+2]; }
        out_pts[wi*3+0] = px; out_pts[wi*3+1] = py; out_pts[wi*3+2] = pz;
    }
}

// ---------------- K8: per-point cosine -> workspace (NO contended atomics) ----------------
__global__ __launch_bounds__(256) void k_loss(const int* __restrict__ match,
                                              const int* __restrict__ valid,
                                              const int* __restrict__ idx,
                                              const float* __restrict__ desc,
                                              const float* __restrict__ mem_desc,
                                              float* __restrict__ cos_ws)
{
    __shared__ float sw[12];
    int p = blockIdx.x;
    int t = threadIdx.x;
    float dv = desc[p * DDIM + t];
    int m = match[p];
    float mv = m ? mem_desc[idx[p] * DDIM + t] : dv;
    float sdd = dv * dv, smm = mv * mv, sdm = dv * mv;
    for (int off = 32; off; off >>= 1) {
        sdd += __shfl_down(sdd, off);
        smm += __shfl_down(smm, off);
        sdm += __shfl_down(sdm, off);
    }
    if ((t & 63) == 0) { int w = t >> 6; sw[w] = sdd; sw[4+w] = smm; sw[8+w] = sdm; }
    __syncthreads();
    if (t == 0) {
        float a = sw[0] + sw[1] + sw[2] + sw[3];
        float b = sw[4] + sw[5] + sw[6] + sw[7];
        float c = sw[8] + sw[9] + sw[10] + sw[11];
        float nd = fmaxf(sqrtf(a), EPSF);
        float nm = fmaxf(sqrtf(b), EPSF);
        float cosv = c / (nd * nm);
        cos_ws[p] = valid[p] ? cosv : 0.f;   // invalid contributes 0 to the sum
    }
}

// ---------------- K9: final single-block reduction over 4096 points ----------------
__global__ __launch_bounds__(256) void k_final(const float* __restrict__ cos_ws,
                                               const int* __restrict__ valid,
                                               float* __restrict__ dout)
{
    __shared__ float ss[256];
    __shared__ float sv[256];
    int t = threadIdx.x;
    float s = 0.f; float v = 0.f;
    for (int k = t; k < P_TOT; k += 256) {
        s += cos_ws[k];
        v += (float)valid[k];
    }
    ss[t] = s; sv[t] = v;
    __syncthreads();
    for (int off = 128; off; off >>= 1) {
        if (t < off) { ss[t] += ss[t + off]; sv[t] += sv[t + off]; }
        __syncthreads();
    }
    if (t == 0) {
        float nv = fmaxf(sv[0], 1.f);
        dout[0] = 1.f - ss[0] / nv;
    }
}

extern "C" void kernel_launch(void* const* d_in, const int* in_sizes, int n_in,
                              void* d_out, int out_size, void* d_ws, size_t ws_size,
                              hipStream_t stream)
{
    const float* points   = (const float*)d_in[0];
    const float* depth    = (const float*)d_in[1];
    const float* pose     = (const float*)d_in[2];
    const float* Kmat     = (const float*)d_in[3];
    const float* desc     = (const float*)d_in[4];
    const float* mem_pts  = (const float*)d_in[5];
    const float* mem_desc = (const float*)d_in[6];
    const int*   next_ptr = (const int*)d_in[7];

    float* out      = (float*)d_out;
    float* out_pts  = out + 2;
    float* out_desc = out + 2 + (long)N_MEM * 3;

    char* ws = (char*)d_ws;
    float4* pts_ws  = (float4*)(ws);                 //  65536 B
    int* valid_ws   = (int*)(ws + 65536);            //  16384 B
    int* idx_ws     = (int*)(ws + 81920);            //  16384 B
    int* match_ws   = (int*)(ws + 98304);            //  16384 B
    int* widx_ws    = (int*)(ws + 114688);           //  16384 B
    int* unm_ws     = (int*)(ws + 131072);           //  16384 B
    int* winner_ws  = (int*)(ws + 147456);           // 200000 B
    float* cos_ws   = (float*)(ws + 347456);         //  16384 B

    // Big partial-argmin arrays live in the not-yet-written out_desc region;
    // they are fully consumed (k_reduce) before k_copy overwrites the region.
    float* part_d = out_desc;                        // 4096*64 floats = 1 MB
    int*   part_i = (int*)(out_desc + P_TOT * CHUNKS);

    hipMemsetAsync(winner_ws, 0xFF, N_MEM * sizeof(int), stream);   // winner = -1

    k_world  <<<16, 256, 0, stream>>>(points, depth, pose, Kmat, pts_ws, valid_ws);
    k_dist   <<<dim3(8, CHUNKS), 256, 0, stream>>>(pts_ws, mem_pts, part_d, part_i);
    k_reduce <<<P_TOT / 4, 256, 0, stream>>>(part_d, part_i, valid_ws, idx_ws, match_ws);
    k_scan   <<<1, 256, 0, stream>>>(match_ws, valid_ws, idx_ws, next_ptr, widx_ws, unm_ws, out);
    k_copy   <<<4096, 256, 0, stream>>>(mem_pts, mem_desc, out_pts, out_desc);
    k_winner <<<P_TOT / 256, 256, 0, stream>>>(widx_ws, winner_ws);
    k_scatter<<<P_TOT, 256, 0, stream>>>(widx_ws, match_ws, unm_ws, winner_ws,
                                         desc, pts_ws, mem_pts, mem_desc, out_pts, out_desc);
    k_loss   <<<P_TOT, 256, 0, stream>>>(match_ws, valid_ws, idx_ws, desc, mem_desc, cos_ws);
    k_final  <<<1, 256, 0, stream>>>(cos_ws, valid_ws, out);
}

// Round 3
// 187.278 us; speedup vs baseline: 1.6468x; 1.1459x over previous
//
#include <hip/hip_runtime.h>
#include <math.h>

#define N_MEM   50000
#define P_TOT   4096
#define DDIM    256
#define HDIM    480
#define WDIM    640
#define CH      128           // distance chunks
#define CHUNK   391           // ceil(50000/128)
#define DISTB   512           // 4 point-blocks x 128 chunks
#define COPYB   256
#define THR2    0.01f
#define EPSF    1e-8f
typedef unsigned long long ull;

// monotone float->uint transform: a<b (float) <=> fsort(a)<fsort(b) (uint)
__device__ __forceinline__ unsigned fsort(float x) {
    unsigned b = __float_as_uint(x);
    return (b & 0x80000000u) ? ~b : (b | 0x80000000u);
}

// ---------------- K1: pix2world + state init ----------------
__global__ void k_world(const float* __restrict__ points,
                        const float* __restrict__ depth,
                        const float* __restrict__ pose,
                        const float* __restrict__ Kmat,
                        float4* __restrict__ pts_out,
                        int* __restrict__ flags_out,
                        ull* __restrict__ minkey)
{
    int p = blockIdx.x * 256 + threadIdx.x;
    if (p >= P_TOT) return;
    minkey[p] = 0xFFFFFFFFFFFFFFFFULL;
    int b = p >> 9;
    const float* K = Kmat + b * 9;
    float a00=K[0],a01=K[1],a02=K[2],a10=K[3],a11=K[4],a12=K[5],a20=K[6],a21=K[7],a22=K[8];
    float det = a00*(a11*a22-a12*a21) - a01*(a10*a22-a12*a20) + a02*(a10*a21-a11*a20);
    float id = 1.0f/det;
    float i00=(a11*a22-a12*a21)*id, i01=(a02*a21-a01*a22)*id, i02=(a01*a12-a02*a11)*id;
    float i10=(a12*a20-a10*a22)*id, i11=(a00*a22-a02*a20)*id, i12=(a02*a10-a00*a12)*id;
    float i20=(a10*a21-a11*a20)*id, i21=(a01*a20-a00*a21)*id, i22=(a00*a11-a01*a10)*id;

    float u = points[p*2+0], v = points[p*2+1];
    float uc = fminf(fmaxf(u, 0.f), (float)WDIM - 1.001f);
    float vc = fminf(fmaxf(v, 0.f), (float)HDIM - 1.001f);
    float u0 = floorf(uc), v0 = floorf(vc);
    float du = uc - u0, dv = vc - v0;
    int u0i = (int)u0, v0i = (int)v0;
    const float* dm = depth + (size_t)b * HDIM * WDIM;
    float d00 = dm[v0i*WDIM + u0i];
    float d01 = dm[v0i*WDIM + u0i + 1];
    float d10 = dm[(v0i+1)*WDIM + u0i];
    float d11 = dm[(v0i+1)*WDIM + u0i + 1];
    float d = d00*(1.f-du)*(1.f-dv) + d01*du*(1.f-dv) + d10*(1.f-du)*dv + d11*du*dv;

    float cx = (i00*u + i01*v + i02) * d;
    float cy = (i10*u + i11*v + i12) * d;
    float cz = (i20*u + i21*v + i22) * d;
    const float* T = pose + b * 12;
    float wx = T[0]*cx + T[1]*cy + T[2]*cz  + T[3];
    float wy = T[4]*cx + T[5]*cy + T[6]*cz  + T[7];
    float wz = T[8]*cx + T[9]*cy + T[10]*cz + T[11];
    int val = (d > 0.f) && isfinite(wx) && isfinite(wy) && isfinite(wz);
    float4 o = val ? make_float4(wx, wy, wz, 0.f) : make_float4(1e6f, 1e6f, 1e6f, 0.f);
    pts_out[p] = o;
    flags_out[p] = val;
}

// ---------------- K2: fused distance-argmin (VALU) + state copy (HBM) ----------------
// blocks [0,512): 4 point-blocks x 128 chunks, 4 pts/thread, float4 LDS entries,
//                 packed-key u64 atomicMin per point (exact (d, j) lexicographic min).
// blocks [512,768): grid-stride copy of mem_pts/mem_desc -> out + winner=-1 init.
__global__ __launch_bounds__(256) void k_main(const float4* __restrict__ pts,
                                              const float* __restrict__ mem_pts,
                                              const float* __restrict__ mem_desc,
                                              ull* __restrict__ minkey,
                                              float* __restrict__ out_pts,
                                              float* __restrict__ out_desc,
                                              int* __restrict__ winner)
{
    __shared__ float4 sm[CHUNK];
    int bid = blockIdx.x;
    int t = threadIdx.x;
    if (bid < DISTB) {
        int pb = bid >> 7;          // 0..3
        int ch = bid & 127;         // 0..127
        int j0 = ch * CHUNK;
        int cnt = min(CHUNK, N_MEM - j0);
        for (int j = t; j < cnt; j += 256) {
            float mx = mem_pts[(j0 + j) * 3 + 0];
            float my = mem_pts[(j0 + j) * 3 + 1];
            float mz = mem_pts[(j0 + j) * 3 + 2];
            sm[j] = make_float4(mx, my, mz, mx*mx + my*my + mz*mz);
        }
        __syncthreads();
        int p0 = pb * 1024 + t;
        float4 P0 = pts[p0], P1 = pts[p0+256], P2 = pts[p0+512], P3 = pts[p0+768];
        float pp0 = P0.x*P0.x + P0.y*P0.y + P0.z*P0.z;
        float pp1 = P1.x*P1.x + P1.y*P1.y + P1.z*P1.z;
        float pp2 = P2.x*P2.x + P2.y*P2.y + P2.z*P2.z;
        float pp3 = P3.x*P3.x + P3.y*P3.y + P3.z*P3.z;
        float bd0 = 3.4e38f, bd1 = 3.4e38f, bd2 = 3.4e38f, bd3 = 3.4e38f;
        int bi0 = 0, bi1 = 0, bi2 = 0, bi3 = 0;
        for (int j = 0; j < cnt; ++j) {
            float4 mv = sm[j];
            float dot0 = P0.x*mv.x + P0.y*mv.y + P0.z*mv.z;
            float dot1 = P1.x*mv.x + P1.y*mv.y + P1.z*mv.z;
            float dot2 = P2.x*mv.x + P2.y*mv.y + P2.z*mv.z;
            float dot3 = P3.x*mv.x + P3.y*mv.y + P3.z*mv.z;
            float d0 = pp0 - 2.f*dot0 + mv.w;      // keep fp expr identical to passing R1
            float d1 = pp1 - 2.f*dot1 + mv.w;
            float d2 = pp2 - 2.f*dot2 + mv.w;
            float d3 = pp3 - 2.f*dot3 + mv.w;
            if (d0 < bd0) { bd0 = d0; bi0 = j0 + j; }  // strict <: first occurrence
            if (d1 < bd1) { bd1 = d1; bi1 = j0 + j; }
            if (d2 < bd2) { bd2 = d2; bi2 = j0 + j; }
            if (d3 < bd3) { bd3 = d3; bi3 = j0 + j; }
        }
        ull k0 = ((ull)fsort(bd0) << 32) | (unsigned)bi0;
        ull k1 = ((ull)fsort(bd1) << 32) | (unsigned)bi1;
        ull k2 = ((ull)fsort(bd2) << 32) | (unsigned)bi2;
        ull k3 = ((ull)fsort(bd3) << 32) | (unsigned)bi3;
        atomicMin(&minkey[p0],       k0);
        atomicMin(&minkey[p0 + 256], k1);
        atomicMin(&minkey[p0 + 512], k2);
        atomicMin(&minkey[p0 + 768], k3);
    } else {
        long i = (long)(bid - DISTB) * 256 + t;
        const long stride = (long)COPYB * 256;
        const float2* ds = (const float2*)mem_desc;
        float2* dd = (float2*)out_desc;                 // 8B-aligned (offset 600008 B)
        for (long k = i; k < (long)N_MEM * DDIM / 2; k += stride) dd[k] = ds[k];
        const float2* ps = (const float2*)mem_pts;
        float2* pd = (float2*)out_pts;
        for (long k = i; k < (long)N_MEM * 3 / 2; k += stride) pd[k] = ps[k];
        for (long k = i; k < N_MEM; k += stride) winner[k] = -1;
    }
}

// ---------------- K3: decode keys, scan unmatched -> widx, winner, n_match ----------------
__global__ __launch_bounds__(256) void k_scan(const ull* __restrict__ minkey,
                                              int* __restrict__ flags,
                                              int* __restrict__ idx_ws,
                                              const int* __restrict__ next_ptr,
                                              int* __restrict__ widx,
                                              int* __restrict__ winner,
                                              float* __restrict__ dout)
{
    __shared__ int su[256];
    __shared__ int smc[256];
    int t = threadIdx.x;
    int base = t * 16;
    const ull thr_key = ((ull)fsort(THR2)) << 32;   // key<thr_key <=> d<THR2 exactly
    int um[16], iv[16];
    int usum = 0, msum = 0;
    for (int k = 0; k < 16; k++) {
        ull key = minkey[base + k];
        int v = flags[base + k] & 1;
        int m = (key < thr_key) && v;
        int u = (!m) && v;
        iv[k] = (int)(key & 0xffffffffULL);
        um[k] = u; usum += u; msum += m;
        flags[base + k] = v | (m << 1) | (u << 2);
    }
    su[t] = usum; smc[t] = msum;
    __syncthreads();
    for (int off = 1; off < 256; off <<= 1) {
        int a = su[t], b = (t >= off) ? su[t - off] : 0;
        int c = smc[t], d = (t >= off) ? smc[t - off] : 0;
        __syncthreads();
        su[t] = a + b; smc[t] = c + d;
        __syncthreads();
    }
    int excl = su[t] - usum;
    int np_ = *next_ptr;
    int run = excl;
    for (int k = 0; k < 16; k++) {
        int wv;
        if (um[k]) { run += 1; wv = (np_ + run - 1) % N_MEM; }
        else       { wv = iv[k]; }
        widx[base + k] = wv;
        idx_ws[base + k] = iv[k];
        atomicMax(&winner[wv], base + k);   // last-write-wins = max p per slot
    }
    if (t == 255) dout[1] = (float)smc[255];   // n_match
}

// ---------------- K4: fused scatter + per-point cosine ----------------
__global__ __launch_bounds__(256) void k_scatloss(const int* __restrict__ widx,
                                                  const int* __restrict__ flags,
                                                  const int* __restrict__ winner,
                                                  const float* __restrict__ desc,
                                                  const float4* __restrict__ pts,
                                                  const float* __restrict__ mem_pts,
                                                  const float* __restrict__ mem_desc,
                                                  float* __restrict__ out_pts,
                                                  float* __restrict__ out_desc,
                                                  float* __restrict__ cos_ws)
{
    __shared__ float red[16];
    int p = blockIdx.x;
    int t = threadIdx.x;
    int f = flags[p];
    int v = f & 1, m = (f >> 1) & 1, u = (f >> 2) & 1;
    int wi = widx[p];
    int win = (winner[wi] == p);
    if (!m && !win) {                       // unmatched/invalid non-winner: loss only
        if (t == 0) cos_ws[p] = v ? 1.f : 0.f;   // unmatched valid: cos(d,d)=1
        return;
    }
    float dsg = desc[p * DDIM + t];
    float old = mem_desc[(long)wi * DDIM + t];   // for matched, wi == idx[p]
    float val, cosv;
    if (m) {
        float up = old * 0.5f + dsg * 0.5f;
        float sdd = dsg * dsg, smm2 = old * old, sdm = dsg * old, suu = up * up;
        for (int off = 32; off; off >>= 1) {
            sdd  += __shfl_xor(sdd,  off);
            smm2 += __shfl_xor(smm2, off);
            sdm  += __shfl_xor(sdm,  off);
            suu  += __shfl_xor(suu,  off);
        }
        int w = t >> 6;
        if ((t & 63) == 0) { red[w] = sdd; red[4+w] = smm2; red[8+w] = sdm; red[12+w] = suu; }
        __syncthreads();
        float dd  = red[0] + red[1] + red[2] + red[3];
        float mm2 = red[4] + red[5] + red[6] + red[7];
        float dm  = red[8] + red[9] + red[10] + red[11];
        float uu  = red[12] + red[13] + red[14] + red[15];
        cosv = dm / (fmaxf(sqrtf(dd), EPSF) * fmaxf(sqrtf(mm2), EPSF));
        val = up / (sqrtf(uu) + EPSF);
    } else {
        cosv = v ? 1.f : 0.f;
        val = u ? dsg : old;                // invalid winner rewrites old value (np semantics)
    }
    if (win) {
        out_desc[(long)wi * DDIM + t] = val;
        if (t == 0) {
            float px, py, pz;
            if (u) { float4 P = pts[p]; px = P.x; py = P.y; pz = P.z; }
            else   { px = mem_pts[wi*3]; py = mem_pts[wi*3+1]; pz = mem_pts[wi*3+2]; }
            out_pts[wi*3+0] = px; out_pts[wi*3+1] = py; out_pts[wi*3+2] = pz;
        }
    }
    if (t == 0) cos_ws[p] = cosv;
}

// ---------------- K5: final reduction over 4096 points ----------------
__global__ __launch_bounds__(256) void k_final(const float* __restrict__ cos_ws,
                                               const int* __restrict__ flags,
                                               float* __restrict__ dout)
{
    __shared__ float ss[256];
    __shared__ float sv[256];
    int t = threadIdx.x;
    float s = 0.f, v = 0.f;
    for (int k = t; k < P_TOT; k += 256) {
        s += cos_ws[k];
        v += (float)(flags[k] & 1);
    }
    ss[t] = s; sv[t] = v;
    __syncthreads();
    for (int off = 128; off; off >>= 1) {
        if (t < off) { ss[t] += ss[t + off]; sv[t] += sv[t + off]; }
        __syncthreads();
    }
    if (t == 0) {
        float nv = fmaxf(sv[0], 1.f);
        dout[0] = 1.f - ss[0] / nv;
    }
}

extern "C" void kernel_launch(void* const* d_in, const int* in_sizes, int n_in,
                              void* d_out, int out_size, void* d_ws, size_t ws_size,
                              hipStream_t stream)
{
    const float* points   = (const float*)d_in[0];
    const float* depth    = (const float*)d_in[1];
    const float* pose     = (const float*)d_in[2];
    const float* Kmat     = (const float*)d_in[3];
    const float* desc     = (const float*)d_in[4];
    const float* mem_pts  = (const float*)d_in[5];
    const float* mem_desc = (const float*)d_in[6];
    const int*   next_ptr = (const int*)d_in[7];

    float* out      = (float*)d_out;
    float* out_pts  = out + 2;
    float* out_desc = out + 2 + (long)N_MEM * 3;

    char* ws = (char*)d_ws;
    float4* pts_ws  = (float4*)(ws);                 //  65536 B
    int* flags_ws   = (int*)(ws + 65536);            //  16384 B
    int* idx_ws     = (int*)(ws + 81920);            //  16384 B
    int* widx_ws    = (int*)(ws + 98304);            //  16384 B
    int* winner_ws  = (int*)(ws + 114688);           // 200000 B -> 314688
    float* cos_ws   = (float*)(ws + 314688);         //  16384 B -> 331072
    ull* minkey_ws  = (ull*)(ws + 331072);           //  32768 B -> 363840 (8B aligned)

    k_world   <<<16, 256, 0, stream>>>(points, depth, pose, Kmat, pts_ws, flags_ws, minkey_ws);
    k_main    <<<DISTB + COPYB, 256, 0, stream>>>(pts_ws, mem_pts, mem_desc, minkey_ws,
                                                  out_pts, out_desc, winner_ws);
    k_scan    <<<1, 256, 0, stream>>>(minkey_ws, flags_ws, idx_ws, next_ptr,
                                      widx_ws, winner_ws, out);
    k_scatloss<<<P_TOT, 256, 0, stream>>>(widx_ws, flags_ws, winner_ws, desc, pts_ws,
                                          mem_pts, mem_desc, out_pts, out_desc, cos_ws);
    k_final   <<<1, 256, 0, stream>>>(cos_ws, flags_ws, out);
}

// Round 4
// 180.215 us; speedup vs baseline: 1.7114x; 1.0392x over previous
//
#include <hip/hip_runtime.h>
#include <math.h>

#define N_MEM   50000
#define P_TOT   4096
#define DDIM    256
#define HDIM    480
#define WDIM    640
#define CHUNK   391           // ceil(50000/128)
#define DISTB   1024          // 8 point-blocks x 128 chunks
#define COPYB   512
#define THR2    0.01f
#define EPSF    1e-8f
typedef unsigned long long ull;

// monotone float->uint transform: a<b (float) <=> fsort(a)<fsort(b) (uint)
__device__ __forceinline__ unsigned fsort(float x) {
    unsigned b = __float_as_uint(x);
    return (b & 0x80000000u) ? ~b : (b | 0x80000000u);
}

// ---------------- K1: pix2world + state init ----------------
__global__ void k_world(const float* __restrict__ points,
                        const float* __restrict__ depth,
                        const float* __restrict__ pose,
                        const float* __restrict__ Kmat,
                        float4* __restrict__ pts_out,
                        int* __restrict__ flags_out,
                        ull* __restrict__ minkey)
{
    int p = blockIdx.x * 256 + threadIdx.x;
    if (p >= P_TOT) return;
    minkey[p] = 0xFFFFFFFFFFFFFFFFULL;
    int b = p >> 9;
    const float* K = Kmat + b * 9;
    float a00=K[0],a01=K[1],a02=K[2],a10=K[3],a11=K[4],a12=K[5],a20=K[6],a21=K[7],a22=K[8];
    float det = a00*(a11*a22-a12*a21) - a01*(a10*a22-a12*a20) + a02*(a10*a21-a11*a20);
    float id = 1.0f/det;
    float i00=(a11*a22-a12*a21)*id, i01=(a02*a21-a01*a22)*id, i02=(a01*a12-a02*a11)*id;
    float i10=(a12*a20-a10*a22)*id, i11=(a00*a22-a02*a20)*id, i12=(a02*a10-a00*a12)*id;
    float i20=(a10*a21-a11*a20)*id, i21=(a01*a20-a00*a21)*id, i22=(a00*a11-a01*a10)*id;

    float u = points[p*2+0], v = points[p*2+1];
    float uc = fminf(fmaxf(u, 0.f), (float)WDIM - 1.001f);
    float vc = fminf(fmaxf(v, 0.f), (float)HDIM - 1.001f);
    float u0 = floorf(uc), v0 = floorf(vc);
    float du = uc - u0, dv = vc - v0;
    int u0i = (int)u0, v0i = (int)v0;
    const float* dm = depth + (size_t)b * HDIM * WDIM;
    float d00 = dm[v0i*WDIM + u0i];
    float d01 = dm[v0i*WDIM + u0i + 1];
    float d10 = dm[(v0i+1)*WDIM + u0i];
    float d11 = dm[(v0i+1)*WDIM + u0i + 1];
    float d = d00*(1.f-du)*(1.f-dv) + d01*du*(1.f-dv) + d10*(1.f-du)*dv + d11*du*dv;

    float cx = (i00*u + i01*v + i02) * d;
    float cy = (i10*u + i11*v + i12) * d;
    float cz = (i20*u + i21*v + i22) * d;
    const float* T = pose + b * 12;
    float wx = T[0]*cx + T[1]*cy + T[2]*cz  + T[3];
    float wy = T[4]*cx + T[5]*cy + T[6]*cz  + T[7];
    float wz = T[8]*cx + T[9]*cy + T[10]*cz + T[11];
    int val = (d > 0.f) && isfinite(wx) && isfinite(wy) && isfinite(wz);
    float4 o = val ? make_float4(wx, wy, wz, 0.f) : make_float4(1e6f, 1e6f, 1e6f, 0.f);
    pts_out[p] = o;
    flags_out[p] = val;
}

// ---------------- K2: fused distance-argmin (VALU) + state copy (HBM) ----------------
// blocks [0,1024): 8 point-blocks x 128 chunks, 2 pts/thread, float4 LDS entries,
//                  packed-key u64 atomicMin per point (exact (d, j) lexicographic min).
// blocks [1024,1536): grid-stride copy of mem_pts/mem_desc -> out + winner=-1 init.
__global__ __launch_bounds__(256) void k_main(const float4* __restrict__ pts,
                                              const float* __restrict__ mem_pts,
                                              const float* __restrict__ mem_desc,
                                              ull* __restrict__ minkey,
                                              float* __restrict__ out_pts,
                                              float* __restrict__ out_desc,
                                              int* __restrict__ winner)
{
    __shared__ float4 sm[CHUNK];
    int bid = blockIdx.x;
    int t = threadIdx.x;
    if (bid < DISTB) {
        int pb = bid >> 7;          // 0..7 (512 pts each)
        int ch = bid & 127;         // 0..127
        int j0 = ch * CHUNK;
        int cnt = min(CHUNK, N_MEM - j0);
        for (int j = t; j < cnt; j += 256) {
            float mx = mem_pts[(j0 + j) * 3 + 0];
            float my = mem_pts[(j0 + j) * 3 + 1];
            float mz = mem_pts[(j0 + j) * 3 + 2];
            sm[j] = make_float4(mx, my, mz, mx*mx + my*my + mz*mz);
        }
        __syncthreads();
        int p0 = pb * 512 + t;
        float4 P0 = pts[p0], P1 = pts[p0+256];
        float pp0 = P0.x*P0.x + P0.y*P0.y + P0.z*P0.z;
        float pp1 = P1.x*P1.x + P1.y*P1.y + P1.z*P1.z;
        float bd0 = 3.4e38f, bd1 = 3.4e38f;
        int bi0 = 0, bi1 = 0;
        for (int j = 0; j < cnt; ++j) {
            float4 mv = sm[j];
            float dot0 = P0.x*mv.x + P0.y*mv.y + P0.z*mv.z;
            float dot1 = P1.x*mv.x + P1.y*mv.y + P1.z*mv.z;
            float d0 = pp0 - 2.f*dot0 + mv.w;      // keep fp expr identical to passing R1
            float d1 = pp1 - 2.f*dot1 + mv.w;
            if (d0 < bd0) { bd0 = d0; bi0 = j0 + j; }  // strict <: first occurrence
            if (d1 < bd1) { bd1 = d1; bi1 = j0 + j; }
        }
        ull k0 = ((ull)fsort(bd0) << 32) | (unsigned)bi0;
        ull k1 = ((ull)fsort(bd1) << 32) | (unsigned)bi1;
        atomicMin(&minkey[p0],       k0);
        atomicMin(&minkey[p0 + 256], k1);
    } else {
        const long tid = (long)(bid - DISTB) * 256 + t;
        const long stride = (long)COPYB * 256;
        const float2* ds = (const float2*)mem_desc;
        float2* dd = (float2*)out_desc;                 // 8B-aligned (offset 600008 B)
        const long ND2 = (long)N_MEM * DDIM / 2;        // 6.4e6 float2
        long k = tid * 4;
        const long stride4 = stride * 4;
        for (; k + 3 < ND2; k += stride4) {             // 4-deep unroll: more loads in flight
            float2 a0 = ds[k+0], a1 = ds[k+1], a2 = ds[k+2], a3 = ds[k+3];
            dd[k+0] = a0; dd[k+1] = a1; dd[k+2] = a2; dd[k+3] = a3;
        }
        for (; k < ND2; ++k) dd[k] = ds[k];
        const float2* ps = (const float2*)mem_pts;
        float2* pd = (float2*)out_pts;
        for (long i = tid; i < (long)N_MEM * 3 / 2; i += stride) pd[i] = ps[i];
        for (long i = tid; i < N_MEM; i += stride) winner[i] = -1;
    }
}

// ---------------- K3: decode keys, scan unmatched -> widx, winner, n_match ----------------
__global__ __launch_bounds__(256) void k_scan(const ull* __restrict__ minkey,
                                              int* __restrict__ flags,
                                              int* __restrict__ idx_ws,
                                              const int* __restrict__ next_ptr,
                                              int* __restrict__ widx,
                                              int* __restrict__ winner,
                                              float* __restrict__ dout)
{
    __shared__ int su[256];
    __shared__ int smc[256];
    int t = threadIdx.x;
    int base = t * 16;
    const ull thr_key = ((ull)fsort(THR2)) << 32;   // key<thr_key <=> d<THR2 exactly
    int um[16], iv[16];
    int usum = 0, msum = 0;
    for (int k = 0; k < 16; k++) {
        ull key = minkey[base + k];
        int v = flags[base + k] & 1;
        int m = (key < thr_key) && v;
        int u = (!m) && v;
        iv[k] = (int)(key & 0xffffffffULL);
        um[k] = u; usum += u; msum += m;
        flags[base + k] = v | (m << 1) | (u << 2);
    }
    su[t] = usum; smc[t] = msum;
    __syncthreads();
    for (int off = 1; off < 256; off <<= 1) {
        int a = su[t], b = (t >= off) ? su[t - off] : 0;
        int c = smc[t], d = (t >= off) ? smc[t - off] : 0;
        __syncthreads();
        su[t] = a + b; smc[t] = c + d;
        __syncthreads();
    }
    int excl = su[t] - usum;
    int np_ = *next_ptr;
    int run = excl;
    for (int k = 0; k < 16; k++) {
        int wv;
        if (um[k]) { run += 1; wv = (np_ + run - 1) % N_MEM; }
        else       { wv = iv[k]; }
        widx[base + k] = wv;
        idx_ws[base + k] = iv[k];
        atomicMax(&winner[wv], base + k);   // last-write-wins = max p per slot
    }
    if (t == 255) dout[1] = (float)smc[255];   // n_match
}

// ---------------- K4: fused scatter + per-point cosine ----------------
__global__ __launch_bounds__(256) void k_scatloss(const int* __restrict__ widx,
                                                  const int* __restrict__ flags,
                                                  const int* __restrict__ winner,
                                                  const float* __restrict__ desc,
                                                  const float4* __restrict__ pts,
                                                  const float* __restrict__ mem_pts,
                                                  const float* __restrict__ mem_desc,
                                                  float* __restrict__ out_pts,
                                                  float* __restrict__ out_desc,
                                                  float* __restrict__ cos_ws)
{
    __shared__ float red[16];
    int p = blockIdx.x;
    int t = threadIdx.x;
    int f = flags[p];
    int v = f & 1, m = (f >> 1) & 1, u = (f >> 2) & 1;
    int wi = widx[p];
    int win = (winner[wi] == p);
    if (!m && !win) {                       // unmatched/invalid non-winner: loss only
        if (t == 0) cos_ws[p] = v ? 1.f : 0.f;   // unmatched valid: cos(d,d)=1
        return;
    }
    float dsg = desc[p * DDIM + t];
    float old = mem_desc[(long)wi * DDIM + t];   // for matched, wi == idx[p]
    float val, cosv;
    if (m) {
        float up = old * 0.5f + dsg * 0.5f;
        float sdd = dsg * dsg, smm2 = old * old, sdm = dsg * old, suu = up * up;
        for (int off = 32; off; off >>= 1) {
            sdd  += __shfl_xor(sdd,  off);
            smm2 += __shfl_xor(smm2, off);
            sdm  += __shfl_xor(sdm,  off);
            suu  += __shfl_xor(suu,  off);
        }
        int w = t >> 6;
        if ((t & 63) == 0) { red[w] = sdd; red[4+w] = smm2; red[8+w] = sdm; red[12+w] = suu; }
        __syncthreads();
        float dd  = red[0] + red[1] + red[2] + red[3];
        float mm2 = red[4] + red[5] + red[6] + red[7];
        float dm  = red[8] + red[9] + red[10] + red[11];
        float uu  = red[12] + red[13] + red[14] + red[15];
        cosv = dm / (fmaxf(sqrtf(dd), EPSF) * fmaxf(sqrtf(mm2), EPSF));
        val = up / (sqrtf(uu) + EPSF);
    } else {
        cosv = v ? 1.f : 0.f;
        val = u ? dsg : old;                // invalid winner rewrites old value (np semantics)
    }
    if (win) {
        out_desc[(long)wi * DDIM + t] = val;
        if (t == 0) {
            float px, py, pz;
            if (u) { float4 P = pts[p]; px = P.x; py = P.y; pz = P.z; }
            else   { px = mem_pts[wi*3]; py = mem_pts[wi*3+1]; pz = mem_pts[wi*3+2]; }
            out_pts[wi*3+0] = px; out_pts[wi*3+1] = py; out_pts[wi*3+2] = pz;
        }
    }
    if (t == 0) cos_ws[p] = cosv;
}

// ---------------- K5: final reduction over 4096 points ----------------
__global__ __launch_bounds__(256) void k_final(const float* __restrict__ cos_ws,
                                               const int* __restrict__ flags,
                                               float* __restrict__ dout)
{
    __shared__ float ss[256];
    __shared__ float sv[256];
    int t = threadIdx.x;
    float s = 0.f, v = 0.f;
    for (int k = t; k < P_TOT; k += 256) {
        s += cos_ws[k];
        v += (float)(flags[k] & 1);
    }
    ss[t] = s; sv[t] = v;
    __syncthreads();
    for (int off = 128; off; off >>= 1) {
        if (t < off) { ss[t] += ss[t + off]; sv[t] += sv[t + off]; }
        __syncthreads();
    }
    if (t == 0) {
        float nv = fmaxf(sv[0], 1.f);
        dout[0] = 1.f - ss[0] / nv;
    }
}

extern "C" void kernel_launch(void* const* d_in, const int* in_sizes, int n_in,
                              void* d_out, int out_size, void* d_ws, size_t ws_size,
                              hipStream_t stream)
{
    const float* points   = (const float*)d_in[0];
    const float* depth    = (const float*)d_in[1];
    const float* pose     = (const float*)d_in[2];
    const float* Kmat     = (const float*)d_in[3];
    const float* desc     = (const float*)d_in[4];
    const float* mem_pts  = (const float*)d_in[5];
    const float* mem_desc = (const float*)d_in[6];
    const int*   next_ptr = (const int*)d_in[7];

    float* out      = (float*)d_out;
    float* out_pts  = out + 2;
    float* out_desc = out + 2 + (long)N_MEM * 3;

    char* ws = (char*)d_ws;
    float4* pts_ws  = (float4*)(ws);                 //  65536 B
    int* flags_ws   = (int*)(ws + 65536);            //  16384 B
    int* idx_ws     = (int*)(ws + 81920);            //  16384 B
    int* widx_ws    = (int*)(ws + 98304);            //  16384 B
    int* winner_ws  = (int*)(ws + 114688);           // 200000 B -> 314688
    float* cos_ws   = (float*)(ws + 314688);         //  16384 B -> 331072
    ull* minkey_ws  = (ull*)(ws + 331072);           //  32768 B -> 363840 (8B aligned)

    k_world   <<<16, 256, 0, stream>>>(points, depth, pose, Kmat, pts_ws, flags_ws, minkey_ws);
    k_main    <<<DISTB + COPYB, 256, 0, stream>>>(pts_ws, mem_pts, mem_desc, minkey_ws,
                                                  out_pts, out_desc, winner_ws);
    k_scan    <<<1, 256, 0, stream>>>(minkey_ws, flags_ws, idx_ws, next_ptr,
                                      widx_ws, winner_ws, out);
    k_scatloss<<<P_TOT, 256, 0, stream>>>(widx_ws, flags_ws, winner_ws, desc, pts_ws,
                                          mem_pts, mem_desc, out_pts, out_desc, cos_ws);
    k_final   <<<1, 256, 0, stream>>>(cos_ws, flags_ws, out);
}

// Round 6
// 176.958 us; speedup vs baseline: 1.7429x; 1.0184x over previous
//
#include <hip/hip_runtime.h>
#include <math.h>

#define N_MEM   50000
#define P_TOT   4096
#define DDIM    256
#define HDIM    480
#define WDIM    640
#define CHUNK   196           // ceil(50000/256)
#define DISTB   1024          // 4 point-blocks x 256 chunks, 4 pts/thread
#define COPYB   512
#define THR2    0.01f
#define EPSF    1e-8f
typedef unsigned long long ull;

// monotone float->uint transform: a<b (float) <=> fsort(a)<fsort(b) (uint)
__device__ __forceinline__ unsigned fsort(float x) {
    unsigned b = __float_as_uint(x);
    return (b & 0x80000000u) ? ~b : (b | 0x80000000u);
}

// ---------------- K1: pix2world + minkey init ----------------
__global__ void k_world(const float* __restrict__ points,
                        const float* __restrict__ depth,
                        const float* __restrict__ pose,
                        const float* __restrict__ Kmat,
                        float4* __restrict__ pts_out,
                        int* __restrict__ flags_out,
                        ull* __restrict__ minkey)
{
    int p = blockIdx.x * 256 + threadIdx.x;
    if (p >= P_TOT) return;
    minkey[p] = 0xFFFFFFFFFFFFFFFFULL;
    int b = p >> 9;
    const float* K = Kmat + b * 9;
    float a00=K[0],a01=K[1],a02=K[2],a10=K[3],a11=K[4],a12=K[5],a20=K[6],a21=K[7],a22=K[8];
    float det = a00*(a11*a22-a12*a21) - a01*(a10*a22-a12*a20) + a02*(a10*a21-a11*a20);
    float id = 1.0f/det;
    float i00=(a11*a22-a12*a21)*id, i01=(a02*a21-a01*a22)*id, i02=(a01*a12-a02*a11)*id;
    float i10=(a12*a20-a10*a22)*id, i11=(a00*a22-a02*a20)*id, i12=(a02*a10-a00*a12)*id;
    float i20=(a10*a21-a11*a20)*id, i21=(a01*a20-a00*a21)*id, i22=(a00*a11-a01*a10)*id;

    float u = points[p*2+0], v = points[p*2+1];
    float uc = fminf(fmaxf(u, 0.f), (float)WDIM - 1.001f);
    float vc = fminf(fmaxf(v, 0.f), (float)HDIM - 1.001f);
    float u0 = floorf(uc), v0 = floorf(vc);
    float du = uc - u0, dv = vc - v0;
    int u0i = (int)u0, v0i = (int)v0;
    const float* dm = depth + (size_t)b * HDIM * WDIM;
    float d00 = dm[v0i*WDIM + u0i];
    float d01 = dm[v0i*WDIM + u0i + 1];
    float d10 = dm[(v0i+1)*WDIM + u0i];
    float d11 = dm[(v0i+1)*WDIM + u0i + 1];
    float d = d00*(1.f-du)*(1.f-dv) + d01*du*(1.f-dv) + d10*(1.f-du)*dv + d11*du*dv;

    float cx = (i00*u + i01*v + i02) * d;
    float cy = (i10*u + i11*v + i12) * d;
    float cz = (i20*u + i21*v + i22) * d;
    const float* T = pose + b * 12;
    float wx = T[0]*cx + T[1]*cy + T[2]*cz  + T[3];
    float wy = T[4]*cx + T[5]*cy + T[6]*cz  + T[7];
    float wz = T[8]*cx + T[9]*cy + T[10]*cz + T[11];
    int val = (d > 0.f) && isfinite(wx) && isfinite(wy) && isfinite(wz);
    float4 o = val ? make_float4(wx, wy, wz, 0.f) : make_float4(1e6f, 1e6f, 1e6f, 0.f);
    pts_out[p] = o;
    flags_out[p] = val;
}

// ---------------- K2: fused distance-argmin (VALU) + state copy (HBM) ----------------
// blocks [0,1024): 4 point-blocks x 256 chunks, 4 pts/thread (halves LDS-pipe load
//                  vs 2 pts/thread: LDS wave-instrs scale with point-blocks).
//                  Packed-key u64 atomicMin per point = exact (d, j) lexicographic min.
// blocks [1024,1536): grid-stride copy of mem_pts/mem_desc -> out.
__global__ __launch_bounds__(256) void k_main(const float4* __restrict__ pts,
                                              const float* __restrict__ mem_pts,
                                              const float* __restrict__ mem_desc,
                                              ull* __restrict__ minkey,
                                              float* __restrict__ out_pts,
                                              float* __restrict__ out_desc)
{
    __shared__ float4 sm[CHUNK];
    int bid = blockIdx.x;
    int t = threadIdx.x;
    if (bid < DISTB) {
        int pb = bid >> 8;          // 0..3 (1024 pts each)
        int ch = bid & 255;         // 0..255
        int j0 = ch * CHUNK;
        int cnt = min(CHUNK, N_MEM - j0);   // last chunk: 20
        if (t < cnt) {
            float mx = mem_pts[(j0 + t) * 3 + 0];
            float my = mem_pts[(j0 + t) * 3 + 1];
            float mz = mem_pts[(j0 + t) * 3 + 2];
            sm[t] = make_float4(mx, my, mz, mx*mx + my*my + mz*mz);
        }
        __syncthreads();
        int p0 = pb * 1024 + t;
        float4 P0 = pts[p0], P1 = pts[p0+256], P2 = pts[p0+512], P3 = pts[p0+768];
        float pp0 = P0.x*P0.x + P0.y*P0.y + P0.z*P0.z;
        float pp1 = P1.x*P1.x + P1.y*P1.y + P1.z*P1.z;
        float pp2 = P2.x*P2.x + P2.y*P2.y + P2.z*P2.z;
        float pp3 = P3.x*P3.x + P3.y*P3.y + P3.z*P3.z;
        float bd0 = 3.4e38f, bd1 = 3.4e38f, bd2 = 3.4e38f, bd3 = 3.4e38f;
        int bi0 = 0, bi1 = 0, bi2 = 0, bi3 = 0;
        for (int j = 0; j < cnt; ++j) {
            float4 mv = sm[j];
            float dot0 = P0.x*mv.x + P0.y*mv.y + P0.z*mv.z;
            float dot1 = P1.x*mv.x + P1.y*mv.y + P1.z*mv.z;
            float dot2 = P2.x*mv.x + P2.y*mv.y + P2.z*mv.z;
            float dot3 = P3.x*mv.x + P3.y*mv.y + P3.z*mv.z;
            float d0 = pp0 - 2.f*dot0 + mv.w;      // fp expr identical to passing R4
            float d1 = pp1 - 2.f*dot1 + mv.w;
            float d2 = pp2 - 2.f*dot2 + mv.w;
            float d3 = pp3 - 2.f*dot3 + mv.w;
            if (d0 < bd0) { bd0 = d0; bi0 = j0 + j; }  // strict <: first occurrence
            if (d1 < bd1) { bd1 = d1; bi1 = j0 + j; }
            if (d2 < bd2) { bd2 = d2; bi2 = j0 + j; }
            if (d3 < bd3) { bd3 = d3; bi3 = j0 + j; }
        }
        atomicMin(&minkey[p0],       ((ull)fsort(bd0) << 32) | (unsigned)bi0);
        atomicMin(&minkey[p0 + 256], ((ull)fsort(bd1) << 32) | (unsigned)bi1);
        atomicMin(&minkey[p0 + 512], ((ull)fsort(bd2) << 32) | (unsigned)bi2);
        atomicMin(&minkey[p0 + 768], ((ull)fsort(bd3) << 32) | (unsigned)bi3);
    } else {
        const long tid = (long)(bid - DISTB) * 256 + t;
        const long stride = (long)COPYB * 256;
        const float2* ds = (const float2*)mem_desc;
        float2* dd = (float2*)out_desc;                 // 8B-aligned (offset 600008 B)
        const long ND2 = (long)N_MEM * DDIM / 2;        // 6.4e6 float2
        long k = tid * 4;
        const long stride4 = stride * 4;
        for (; k + 3 < ND2; k += stride4) {             // 4-deep unroll: loads in flight
            float2 a0 = ds[k+0], a1 = ds[k+1], a2 = ds[k+2], a3 = ds[k+3];
            dd[k+0] = a0; dd[k+1] = a1; dd[k+2] = a2; dd[k+3] = a3;
        }
        for (; k < ND2; ++k) dd[k] = ds[k];
        const float2* ps = (const float2*)mem_pts;
        float2* pd = (float2*)out_pts;
        for (long i = tid; i < (long)N_MEM * 3 / 2; i += stride) pd[i] = ps[i];
    }
}

// ---------------- K3: decode keys, scan unmatched -> widx, winner, n_match ----------------
// Winner init: only the <=4096 touched slots need init -> plain stores + barrier,
// then atomicMax. No 200KB global memset needed.
__global__ __launch_bounds__(256) void k_scan(const ull* __restrict__ minkey,
                                              int* __restrict__ flags,
                                              const int* __restrict__ next_ptr,
                                              int* __restrict__ widx,
                                              int* __restrict__ winner,
                                              float* __restrict__ dout)
{
    __shared__ int su[256];
    __shared__ int smc[256];
    int t = threadIdx.x;
    int base = t * 16;
    const ull thr_key = ((ull)fsort(THR2)) << 32;   // key<thr_key <=> d<THR2 exactly
    int um[16], iv[16], wvv[16];
    int usum = 0, msum = 0;
    for (int k = 0; k < 16; k++) {
        ull key = minkey[base + k];
        int v = flags[base + k] & 1;
        int m = (key < thr_key) && v;
        int u = (!m) && v;
        iv[k] = (int)(key & 0xffffffffULL);
        um[k] = u; usum += u; msum += m;
        flags[base + k] = v | (m << 1) | (u << 2);
    }
    su[t] = usum; smc[t] = msum;
    __syncthreads();
    for (int off = 1; off < 256; off <<= 1) {
        int a = su[t], b = (t >= off) ? su[t - off] : 0;
        int c = smc[t], d = (t >= off) ? smc[t - off] : 0;
        __syncthreads();
        su[t] = a + b; smc[t] = c + d;
        __syncthreads();
    }
    int excl = su[t] - usum;
    int np_ = *next_ptr;
    int run = excl;
    for (int k = 0; k < 16; k++) {
        int wv;
        if (um[k]) { run += 1; wv = (np_ + run - 1) % N_MEM; }
        else       { wv = iv[k]; }
        widx[base + k] = wv;
        wvv[k] = wv;
        winner[wv] = -1;                   // init touched slots (racing -1 stores benign)
    }
    __syncthreads();
    for (int k = 0; k < 16; k++)
        atomicMax(&winner[wvv[k]], base + k);   // last-write-wins = max p per slot
    if (t == 255) dout[1] = (float)smc[255];    // n_match
}

// ---------------- K4: fused scatter + per-point cosine ----------------
__global__ __launch_bounds__(256) void k_scatloss(const int* __restrict__ widx,
                                                  const int* __restrict__ flags,
                                                  const int* __restrict__ winner,
                                                  const float* __restrict__ desc,
                                                  const float4* __restrict__ pts,
                                                  const float* __restrict__ mem_pts,
                                                  const float* __restrict__ mem_desc,
                                                  float* __restrict__ out_pts,
                                                  float* __restrict__ out_desc,
                                                  float* __restrict__ cos_ws)
{
    __shared__ float red[16];
    int p = blockIdx.x;
    int t = threadIdx.x;
    int f = flags[p];
    int v = f & 1, m = (f >> 1) & 1, u = (f >> 2) & 1;
    int wi = widx[p];
    int win = (winner[wi] == p);
    if (!m && !win) {                       // unmatched/invalid non-winner: loss only
        if (t == 0) cos_ws[p] = v ? 1.f : 0.f;   // unmatched valid: cos(d,d)=1
        return;
    }
    float dsg = desc[p * DDIM + t];
    float old = mem_desc[(long)wi * DDIM + t];   // for matched, wi == idx[p]
    float val, cosv;
    if (m) {
        float up = old * 0.5f + dsg * 0.5f;
        float sdd = dsg * dsg, smm2 = old * old, sdm = dsg * old, suu = up * up;
        for (int off = 32; off; off >>= 1) {
            sdd  += __shfl_xor(sdd,  off);
            smm2 += __shfl_xor(smm2, off);
            sdm  += __shfl_xor(sdm,  off);
            suu  += __shfl_xor(suu,  off);
        }
        int w = t >> 6;
        if ((t & 63) == 0) { red[w] = sdd; red[4+w] = smm2; red[8+w] = sdm; red[12+w] = suu; }
        __syncthreads();
        float dd  = red[0] + red[1] + red[2] + red[3];
        float mm2 = red[4] + red[5] + red[6] + red[7];
        float dm  = red[8] + red[9] + red[10] + red[11];
        float uu  = red[12] + red[13] + red[14] + red[15];
        cosv = dm / (fmaxf(sqrtf(dd), EPSF) * fmaxf(sqrtf(mm2), EPSF));
        val = up / (sqrtf(uu) + EPSF);
    } else {
        cosv = v ? 1.f : 0.f;
        val = u ? dsg : old;                // invalid winner rewrites old value (np semantics)
    }
    if (win) {
        out_desc[(long)wi * DDIM + t] = val;
        if (t == 0) {
            float px, py, pz;
            if (u) { float4 P = pts[p]; px = P.x; py = P.y; pz = P.z; }
            else   { px = mem_pts[wi*3]; py = mem_pts[wi*3+1]; pz = mem_pts[wi*3+2]; }
            out_pts[wi*3+0] = px; out_pts[wi*3+1] = py; out_pts[wi*3+2] = pz;
        }
    }
    if (t == 0) cos_ws[p] = cosv;
}

// ---------------- K5: final reduction over 4096 points ----------------
__global__ __launch_bounds__(256) void k_final(const float* __restrict__ cos_ws,
                                               const int* __restrict__ flags,
                                               float* __restrict__ dout)
{
    __shared__ float ss[256];
    __shared__ float sv[256];
    int t = threadIdx.x;
    float s = 0.f, v = 0.f;
    for (int k = t; k < P_TOT; k += 256) {
        s += cos_ws[k];
        v += (float)(flags[k] & 1);
    }
    ss[t] = s; sv[t] = v;
    __syncthreads();
    for (int off = 128; off; off >>= 1) {
        if (t < off) { ss[t] += ss[t + off]; sv[t] += sv[t + off]; }
        __syncthreads();
    }
    if (t == 0) {
        float nv = fmaxf(sv[0], 1.f);
        dout[0] = 1.f - ss[0] / nv;
    }
}

extern "C" void kernel_launch(void* const* d_in, const int* in_sizes, int n_in,
                              void* d_out, int out_size, void* d_ws, size_t ws_size,
                              hipStream_t stream)
{
    const float* points   = (const float*)d_in[0];
    const float* depth    = (const float*)d_in[1];
    const float* pose     = (const float*)d_in[2];
    const float* Kmat     = (const float*)d_in[3];
    const float* desc     = (const float*)d_in[4];
    const float* mem_pts  = (const float*)d_in[5];
    const float* mem_desc = (const float*)d_in[6];
    const int*   next_ptr = (const int*)d_in[7];

    float* out      = (float*)d_out;
    float* out_pts  = out + 2;
    float* out_desc = out + 2 + (long)N_MEM * 3;

    char* ws = (char*)d_ws;
    float4* pts_ws  = (float4*)(ws);                 //  65536 B
    int* flags_ws   = (int*)(ws + 65536);            //  16384 B
    int* widx_ws    = (int*)(ws + 81920);            //  16384 B
    int* winner_ws  = (int*)(ws + 98304);            // 200000 B -> 298304
    float* cos_ws   = (float*)(ws + 298304);         //  16384 B -> 314688
    ull* minkey_ws  = (ull*)(ws + 314688);           //  32768 B -> 347456 (8B aligned)

    k_world   <<<16, 256, 0, stream>>>(points, depth, pose, Kmat, pts_ws, flags_ws, minkey_ws);
    k_main    <<<DISTB + COPYB, 256, 0, stream>>>(pts_ws, mem_pts, mem_desc, minkey_ws,
                                                  out_pts, out_desc);
    k_scan    <<<1, 256, 0, stream>>>(minkey_ws, flags_ws, next_ptr,
                                      widx_ws, winner_ws, out);
    k_scatloss<<<P_TOT, 256, 0, stream>>>(widx_ws, flags_ws, winner_ws, desc, pts_ws,
                                          mem_pts, mem_desc, out_pts, out_desc, cos_ws);
    k_final   <<<1, 256, 0, stream>>>(cos_ws, flags_ws, out);
}